// Round 4
// baseline (487.792 us; speedup 1.0000x reference)
//
#include <hip/hip_runtime.h>

#define PADH 68   // row pitch (floats) for 64-col LDS tiles (float4-aligned, breaks stride-64 banks)
#define SUMP 12   // s_sum row pitch (float4-aligned)

__device__ __forceinline__ float sigm_(float x) { return 1.0f / (1.0f + __expf(-x)); }
__device__ __forceinline__ float tanh_(float x) {
    x = fminf(fmaxf(x, -15.0f), 15.0f);
    const float e = __expf(2.0f * x);
    return (e - 1.0f) / (e + 1.0f);
}

// 2 batch rows per block; 512 threads = 8 waves; each wave = 2 rows x 32 nodes.
// All weight indices wave-uniform (w + loop vars) -> scalar s_load via K$.
// 8 waves @ 63.8 KB LDS -> 2 blocks/CU = 16 waves/CU (~50% occ), vs R3's 8.
// Cross-wave edge-sum via ds_add_f32 (atomicAdd on LDS) -> no per-wave buffers.
__global__ __launch_bounds__(512, 4) void gnn_fused(
    const float* __restrict__ init_features,  // (B,32,3)
    const float* __restrict__ edge_weight,    // (B,992)
    const float* __restrict__ noise_info,     // (B,1)
    const float* __restrict__ hx_init,        // (B,32,64)
    const float* __restrict__ x_hat,          // (B,32)
    const float* __restrict__ var_in,         // (B,32)
    const float* __restrict__ W1a, const float* __restrict__ b1a,
    const float* __restrict__ W2a, const float* __restrict__ b2a,
    const float* __restrict__ W2b, const float* __restrict__ b2b,
    const float* __restrict__ W2c, const float* __restrict__ b2c,
    const float* __restrict__ W3a, const float* __restrict__ b3a,
    const float* __restrict__ W3b, const float* __restrict__ b3b,
    const float* __restrict__ W3c, const float* __restrict__ b3c,
    const float* __restrict__ Wih, const float* __restrict__ Whh,
    const float* __restrict__ bih, const float* __restrict__ bhh,
    const float* __restrict__ W4,  const float* __restrict__ b4,
    float* __restrict__ out)                  // (B,32,4)
{
    const int t  = threadIdx.x;
    const int w  = __builtin_amdgcn_readfirstlane(t >> 6); // wave id 0..7, SGPR-uniform
    const int l  = t & 63;    // node slot = bl*32 + a
    const int bl = l >> 5;    // local batch row (0/1)
    const int a  = l & 31;    // node index
    const int b0 = blockIdx.x * 2;
    const int bg = b0 + bl;   // global batch row for this lane

    __shared__ float s_edge[1984];        // [2][992]
    __shared__ float s_A1[64][PADH];      // nodes@W2a[0:8]+b2a+nw*W2a[17]; later v1 scratch
    __shared__ float s_B1[64][PADH];      // nodes@W2a[8:16];               later v2 scratch
    __shared__ float s_hx[64][PADH];      // GRU hidden state
    __shared__ float s_nodes[64][8];      // node features / gru_read
    __shared__ float s_sum[64][SUMP];     // edge-sum accumulator (ds_add_f32)

    // ---- stage per-block data (coalesced) ----
    for (int i = t; i < 1984; i += 512) s_edge[i] = edge_weight[(size_t)b0*992 + i];
    for (int i = t; i < 4096; i += 512) s_hx[i >> 6][i & 63] = hx_init[(size_t)b0*2048 + i];
    const float nw = noise_info[bg];

    // ---- iteration-0 nodes: x_init(5) @ W1a(5,8) + b1a; wave 0 does all 8 channels ----
    if (w == 0) {
        const float* f = init_features + ((size_t)bg*32 + a)*3;
        const float xi0 = f[0], xi1 = f[1], xi2 = f[2];
        const float xi3 = x_hat[(size_t)bg*32 + a];
        const float xi4 = var_in[(size_t)bg*32 + a];
        #pragma unroll
        for (int c = 0; c < 8; ++c) {
            float acc = b1a[c];
            acc = __builtin_fmaf(xi0, W1a[0*8+c], acc);
            acc = __builtin_fmaf(xi1, W1a[1*8+c], acc);
            acc = __builtin_fmaf(xi2, W1a[2*8+c], acc);
            acc = __builtin_fmaf(xi3, W1a[3*8+c], acc);
            acc = __builtin_fmaf(xi4, W1a[4*8+c], acc);
            s_nodes[l][c] = acc;
        }
    }
    __syncthreads();

    #pragma unroll 1
    for (int it = 0; it < 3; ++it) {
        // ---- zero edge-sum accumulator (read by prev iter's GRU ended before barD) ----
        for (int i = t; i < 64*SUMP; i += 512) ((float*)s_sum)[i] = 0.0f;

        // ---- A: fold layer-1: A1 = nodes@W2a[0:8]+b2a+nw*W2a[17], B1 = nodes@W2a[8:16].
        //      wave w covers h = w*8 .. w*8+7 (uniform weight indices). ----
        {
            float nd[8];
            *(float4*)&nd[0] = *(const float4*)&s_nodes[l][0];
            *(float4*)&nd[4] = *(const float4*)&s_nodes[l][4];
            #pragma unroll
            for (int hh = 0; hh < 8; ++hh) {
                const int h = w*8 + hh;
                float accA = __builtin_fmaf(nw, W2a[1088 + h], b2a[h]);
                float accB = 0.0f;
                #pragma unroll
                for (int k = 0; k < 8; ++k) {
                    accA = __builtin_fmaf(nd[k], W2a[k*64 + h],     accA);
                    accB = __builtin_fmaf(nd[k], W2a[(8+k)*64 + h], accB);
                }
                s_A1[l][h] = accA;
                s_B1[l][h] = accB;
            }
        }
        __syncthreads();

        // ---- B: edge MLP. Wave w handles edges j = w + 8i of every node. ----
        float accout[8];
        #pragma unroll
        for (int c = 0; c < 8; ++c) accout[c] = 0.0f;

        #pragma unroll 1
        for (int i = 0; i < 4; ++i) {
            const int j = w + 8*i;            // uniform; wave 7 skips j==31
            if (j < 31) {
                const int tbv = (j < a) ? j : (j + 1);
                const float ew = s_edge[bl*992 + a*31 + j];
                float m2[32];
                #pragma unroll
                for (int n = 0; n < 32; ++n) m2[n] = b2b[n];
                #pragma unroll 1
                for (int kb = 0; kb < 4; ++kb) {          // stream L1 -> L2 in k-blocks of 16
                    float m1[16];
                    #pragma unroll
                    for (int q = 0; q < 4; ++q) {
                        const int h = kb*16 + q*4;
                        const float4 A4 = *(const float4*)&s_A1[l][h];
                        const float4 B4 = *(const float4*)&s_B1[bl*32 + tbv][h];
                        m1[q*4+0] = fmaxf(__builtin_fmaf(ew, W2a[1024+h+0], A4.x + B4.x), 0.f);
                        m1[q*4+1] = fmaxf(__builtin_fmaf(ew, W2a[1024+h+1], A4.y + B4.y), 0.f);
                        m1[q*4+2] = fmaxf(__builtin_fmaf(ew, W2a[1024+h+2], A4.z + B4.z), 0.f);
                        m1[q*4+3] = fmaxf(__builtin_fmaf(ew, W2a[1024+h+3], A4.w + B4.w), 0.f);
                    }
                    #pragma unroll
                    for (int kk = 0; kk < 16; ++kk) {      // W2b idx uniform -> s_load
                        #pragma unroll
                        for (int n = 0; n < 32; ++n)
                            m2[n] = __builtin_fmaf(m1[kk], W2b[(kb*16+kk)*32 + n], m2[n]);
                    }
                }
                #pragma unroll
                for (int n = 0; n < 32; ++n) m2[n] = fmaxf(m2[n], 0.f);
                #pragma unroll
                for (int c = 0; c < 8; ++c) {
                    float acc = b2c[c];
                    #pragma unroll
                    for (int n = 0; n < 32; ++n)
                        acc = __builtin_fmaf(m2[n], W2c[n*8 + c], acc);
                    accout[c] += fmaxf(acc, 0.f);
                }
            }
        }
        #pragma unroll
        for (int c = 0; c < 8; ++c) atomicAdd(&s_sum[l][c], accout[c]);   // ds_add_f32
        __syncthreads();

        // ---- C: GRU. Lane owns node (bl,a); wave w owns channels c = w*8..+7. ----
        float h[64];                          // static-indexed only (rule #20)
        #pragma unroll
        for (int q = 0; q < 16; ++q)
            *(float4*)&h[q*4] = *(const float4*)&s_hx[l][q*4];
        float x8[8];
        *(float4*)&x8[0] = *(const float4*)&s_sum[l][0];
        *(float4*)&x8[4] = *(const float4*)&s_sum[l][4];
        __syncthreads();                      // every wave captured h_old before any write

        #pragma unroll 1
        for (int cc = 0; cc < 8; ++cc) {
            const int c = w*8 + cc;           // uniform -> Wih/Whh/bias all s_load
            float r0 = bih[c]      + bhh[c];
            float z0 = bih[64+c]   + bhh[64+c];
            float n0 = bih[128+c];
            float nh = bhh[128+c];
            #pragma unroll
            for (int k = 0; k < 8; ++k) {
                r0 = __builtin_fmaf(x8[k], Wih[c*8+k],        r0);
                z0 = __builtin_fmaf(x8[k], Wih[(64+c)*8+k],   z0);
                n0 = __builtin_fmaf(x8[k], Wih[(128+c)*8+k],  n0);
            }
            #pragma unroll
            for (int k = 0; k < 64; ++k) {
                r0 = __builtin_fmaf(h[k], Whh[c*64+k],        r0);
                z0 = __builtin_fmaf(h[k], Whh[(64+c)*64+k],   z0);
                nh = __builtin_fmaf(h[k], Whh[(128+c)*64+k],  nh);
            }
            const float rr = sigm_(r0);
            const float zz = sigm_(z0);
            const float nn = tanh_(n0 + rr*nh);
            const float hold = s_hx[l][c];    // still old: only this lane writes (l,c)
            s_hx[l][c] = (1.0f - zz)*nn + zz*hold;
        }
        __syncthreads();

        // ---- D: gru_read = hx_new @ W4 + b4; wave w does channel w ----
        {
            float acc = b4[w];
            #pragma unroll
            for (int q = 0; q < 16; ++q) {
                const float4 hv = *(const float4*)&s_hx[l][q*4];
                acc = __builtin_fmaf(hv.x, W4[(q*4+0)*8 + w], acc);
                acc = __builtin_fmaf(hv.y, W4[(q*4+1)*8 + w], acc);
                acc = __builtin_fmaf(hv.z, W4[(q*4+2)*8 + w], acc);
                acc = __builtin_fmaf(hv.w, W4[(q*4+3)*8 + w], acc);
            }
            s_nodes[l][w] = acc;
        }
        __syncthreads();
    }

    // ---- final MLP: 8 -> 64 -> 32 -> 4 (no activations) ----
    {   // v1 = nodes@W3a + b3a; wave w covers h = w*8..+7; store in s_A1
        float nd[8];
        *(float4*)&nd[0] = *(const float4*)&s_nodes[l][0];
        *(float4*)&nd[4] = *(const float4*)&s_nodes[l][4];
        #pragma unroll
        for (int hh = 0; hh < 8; ++hh) {
            const int hO = w*8 + hh;
            float acc = b3a[hO];
            #pragma unroll
            for (int k = 0; k < 8; ++k) acc = __builtin_fmaf(nd[k], W3a[k*64 + hO], acc);
            s_A1[l][hO] = acc;
        }
    }
    __syncthreads();
    {   // v2 = v1@W3b + b3b; wave w covers outputs n = w*4..+3; store in s_B1
        float acc[4];
        #pragma unroll
        for (int jj = 0; jj < 4; ++jj) acc[jj] = b3b[w*4 + jj];
        #pragma unroll
        for (int q = 0; q < 16; ++q) {
            const float4 v = *(const float4*)&s_A1[l][q*4];
            #pragma unroll
            for (int jj = 0; jj < 4; ++jj) {
                const int n = w*4 + jj;
                acc[jj] = __builtin_fmaf(v.x, W3b[(q*4+0)*32 + n], acc[jj]);
                acc[jj] = __builtin_fmaf(v.y, W3b[(q*4+1)*32 + n], acc[jj]);
                acc[jj] = __builtin_fmaf(v.z, W3b[(q*4+2)*32 + n], acc[jj]);
                acc[jj] = __builtin_fmaf(v.w, W3b[(q*4+3)*32 + n], acc[jj]);
            }
        }
        #pragma unroll
        for (int jj = 0; jj < 4; ++jj) s_B1[l][w*4 + jj] = acc[jj];
    }
    __syncthreads();
    if (w < 4) {   // z = v2@W3c + b3c; wave w writes output channel w (NC=4)
        float acc = b3c[w];
        #pragma unroll
        for (int n = 0; n < 32; ++n)
            acc = __builtin_fmaf(s_B1[l][n], W3c[n*4 + w], acc);
        out[((size_t)bg*32 + a)*4 + w] = acc;
    }
}

extern "C" void kernel_launch(void* const* d_in, const int* in_sizes, int n_in,
                              void* d_out, int out_size, void* d_ws, size_t ws_size,
                              hipStream_t stream)
{
    const float* init_features = (const float*)d_in[0];
    const float* edge_weight   = (const float*)d_in[1];
    const float* noise_info    = (const float*)d_in[2];
    const float* hx_init       = (const float*)d_in[3];
    /* d_in[4] = cons — unused by the reference forward */
    const float* x_hat = (const float*)d_in[5];
    const float* var_i = (const float*)d_in[6];
    const float* W1a = (const float*)d_in[7];  const float* b1a = (const float*)d_in[8];
    const float* W2a = (const float*)d_in[9];  const float* b2a = (const float*)d_in[10];
    const float* W2b = (const float*)d_in[11]; const float* b2b = (const float*)d_in[12];
    const float* W2c = (const float*)d_in[13]; const float* b2c = (const float*)d_in[14];
    const float* W3a = (const float*)d_in[15]; const float* b3a = (const float*)d_in[16];
    const float* W3b = (const float*)d_in[17]; const float* b3b = (const float*)d_in[18];
    const float* W3c = (const float*)d_in[19]; const float* b3c = (const float*)d_in[20];
    const float* Wih = (const float*)d_in[21]; const float* Whh = (const float*)d_in[22];
    const float* bih = (const float*)d_in[23]; const float* bhh = (const float*)d_in[24];
    const float* W4  = (const float*)d_in[25]; const float* b4  = (const float*)d_in[26];

    gnn_fused<<<dim3(512), dim3(512), 0, stream>>>(
        init_features, edge_weight, noise_info, hx_init, x_hat, var_i,
        W1a, b1a, W2a, b2a, W2b, b2b, W2c, b2c,
        W3a, b3a, W3b, b3b, W3c, b3c,
        Wih, Whh, bih, bhh, W4, b4, (float*)d_out);
}

// Round 7
// 416.413 us; speedup vs baseline: 1.1714x; 1.1714x over previous
//
#include <hip/hip_runtime.h>

#define PADH 68   // row pitch (floats) for 64-col LDS tiles

typedef float v2f __attribute__((ext_vector_type(2)));

__device__ __forceinline__ v2f v2ld(const float* p) { return *(const v2f*)p; }   // 8B-aligned
__device__ __forceinline__ v2f v2fma(v2f a, v2f b, v2f c) { return __builtin_elementwise_fma(a, b, c); }
__device__ __forceinline__ v2f v2max0(v2f a) { v2f z = {0.f, 0.f}; return __builtin_elementwise_max(a, z); }

__device__ __forceinline__ float sigm_(float x) { return 1.0f / (1.0f + __expf(-x)); }
__device__ __forceinline__ float tanh_(float x) {
    x = fminf(fmaxf(x, -15.0f), 15.0f);
    const float e = __expf(2.0f * x);
    return (e - 1.0f) / (e + 1.0f);
}

// R3 structure (2 batch rows/block, 4 waves, wave-uniform weight indices ->
// s_load; 331 us baseline) + packed-fp32 (v_pk_fma_f32) on all dominant dots.
// R6 bugfix: removed the stray 8-lane shfl_xor reduce — in this decomposition
// lane l IS the node slot; cross-wave combining is s_part + phase-C sum ONLY.
__global__ __launch_bounds__(256, 2) void gnn_fused(
    const float* __restrict__ init_features,  // (B,32,3)
    const float* __restrict__ edge_weight,    // (B,992)
    const float* __restrict__ noise_info,     // (B,1)
    const float* __restrict__ hx_init,        // (B,32,64)
    const float* __restrict__ x_hat,
    const float* __restrict__ var_in,
    const float* __restrict__ W1a, const float* __restrict__ b1a,
    const float* __restrict__ W2a, const float* __restrict__ b2a,
    const float* __restrict__ W2b, const float* __restrict__ b2b,
    const float* __restrict__ W2c, const float* __restrict__ b2c,
    const float* __restrict__ W3a, const float* __restrict__ b3a,
    const float* __restrict__ W3b, const float* __restrict__ b3b,
    const float* __restrict__ W3c, const float* __restrict__ b3c,
    const float* __restrict__ Wih, const float* __restrict__ Whh,
    const float* __restrict__ bih, const float* __restrict__ bhh,
    const float* __restrict__ W4,  const float* __restrict__ b4,
    float* __restrict__ out)                  // (B,32,4)
{
    const int t  = threadIdx.x;
    const int w  = __builtin_amdgcn_readfirstlane(t >> 6); // wave id 0..3
    const int l  = t & 63;    // node slot = bl*32 + a
    const int bl = l >> 5;
    const int a  = l & 31;
    const int b0 = blockIdx.x * 2;
    const int bg = b0 + bl;

    __shared__ float s_edge[1984];        // [2][992]
    __shared__ float s_A1[64][PADH];
    __shared__ float s_B1[64][PADH];
    __shared__ float s_hx[64][PADH];
    __shared__ float s_nodes[64][8];
    __shared__ float s_part[4][64][9];

    for (int i = t; i < 1984; i += 256) s_edge[i] = edge_weight[(size_t)b0*992 + i];
    for (int i = t; i < 4096; i += 256) s_hx[i >> 6][i & 63] = hx_init[(size_t)b0*2048 + i];
    const float nw = noise_info[bg];
    const v2f nwp = {nw, nw};

    // ---- iteration-0 nodes: x_init(5) @ W1a(5,8) + b1a; wave w does channels w*2,w*2+1
    {
        const float* f = init_features + ((size_t)bg*32 + a)*3;
        const float xi0 = f[0], xi1 = f[1], xi2 = f[2];
        const float xi3 = x_hat[(size_t)bg*32 + a];
        const float xi4 = var_in[(size_t)bg*32 + a];
        #pragma unroll
        for (int cc = 0; cc < 2; ++cc) {
            const int c = w*2 + cc;
            float acc = b1a[c];
            acc = __builtin_fmaf(xi0, W1a[0*8+c], acc);
            acc = __builtin_fmaf(xi1, W1a[1*8+c], acc);
            acc = __builtin_fmaf(xi2, W1a[2*8+c], acc);
            acc = __builtin_fmaf(xi3, W1a[3*8+c], acc);
            acc = __builtin_fmaf(xi4, W1a[4*8+c], acc);
            s_nodes[l][c] = acc;
        }
    }
    __syncthreads();

    #pragma unroll 1
    for (int it = 0; it < 3; ++it) {
        // ---- A: A1 = nodes@W2a[0:8]+b2a+nw*W2a[17]; B1 = nodes@W2a[8:16].
        //      wave w covers h = w*16..+15, packed over h-pairs. ----
        {
            float nd[8];
            *(float4*)&nd[0] = *(const float4*)&s_nodes[l][0];
            *(float4*)&nd[4] = *(const float4*)&s_nodes[l][4];
            const int h0 = w*16;
            v2f aA[8], aB[8];
            #pragma unroll
            for (int hp = 0; hp < 8; ++hp) {
                aA[hp] = v2fma(nwp, v2ld(&W2a[1088 + h0 + 2*hp]), v2ld(&b2a[h0 + 2*hp]));
                aB[hp] = (v2f){0.f, 0.f};
            }
            #pragma unroll
            for (int k = 0; k < 8; ++k) {
                const v2f ndk = {nd[k], nd[k]};
                #pragma unroll
                for (int hp = 0; hp < 8; ++hp) {
                    aA[hp] = v2fma(ndk, v2ld(&W2a[k*64     + h0 + 2*hp]), aA[hp]);
                    aB[hp] = v2fma(ndk, v2ld(&W2a[(8+k)*64 + h0 + 2*hp]), aB[hp]);
                }
            }
            #pragma unroll
            for (int hp = 0; hp < 8; ++hp) {
                *(v2f*)&s_A1[l][h0 + 2*hp] = aA[hp];   // 272l + even*4 bytes: 8B-aligned
                *(v2f*)&s_B1[l][h0 + 2*hp] = aB[hp];
            }
        }
        __syncthreads();

        // ---- B: edge MLP; wave w handles edges j = w + 4i of lane's node. Packed. ----
        v2f accoutp[4];
        #pragma unroll
        for (int cp = 0; cp < 4; ++cp) accoutp[cp] = (v2f){0.f, 0.f};

        #pragma unroll 1
        for (int i = 0; i < 8; ++i) {
            const int j = w + 4*i;            // uniform; wave 3 skips j==31
            if (j < 31) {
                const int tbv = (j < a) ? j : (j + 1);
                const float ew = s_edge[bl*992 + a*31 + j];
                const v2f ewp = {ew, ew};
                v2f m2p[16];
                #pragma unroll
                for (int p = 0; p < 16; ++p) m2p[p] = v2ld(&b2b[2*p]);
                #pragma unroll 1
                for (int kb = 0; kb < 4; ++kb) {
                    v2f m1p[8];
                    #pragma unroll
                    for (int hp = 0; hp < 8; ++hp) {
                        const int h = kb*16 + 2*hp;
                        v2f tv = v2ld(&s_A1[l][h]) + v2ld(&s_B1[bl*32 + tbv][h]);
                        tv = v2fma(ewp, v2ld(&W2a[1024 + h]), tv);
                        m1p[hp] = v2max0(tv);
                    }
                    #pragma unroll
                    for (int kkp = 0; kkp < 8; ++kkp) {   // W2b rows: uniform -> s_load
                        const float* wr0 = &W2b[(kb*16 + 2*kkp)*32];
                        const v2f mlo = {m1p[kkp].x, m1p[kkp].x};
                        #pragma unroll
                        for (int p = 0; p < 16; ++p)
                            m2p[p] = v2fma(mlo, v2ld(&wr0[2*p]), m2p[p]);
                        const v2f mhi = {m1p[kkp].y, m1p[kkp].y};
                        #pragma unroll
                        for (int p = 0; p < 16; ++p)
                            m2p[p] = v2fma(mhi, v2ld(&wr0[32 + 2*p]), m2p[p]);
                    }
                }
                #pragma unroll
                for (int p = 0; p < 16; ++p) m2p[p] = v2max0(m2p[p]);
                // L3: 32 -> 8, packed over channel pairs
                v2f acc3[4];
                #pragma unroll
                for (int cp = 0; cp < 4; ++cp) acc3[cp] = v2ld(&b2c[2*cp]);
                #pragma unroll
                for (int p = 0; p < 16; ++p) {
                    const v2f mx = {m2p[p].x, m2p[p].x};
                    const v2f my = {m2p[p].y, m2p[p].y};
                    #pragma unroll
                    for (int cp = 0; cp < 4; ++cp) {
                        acc3[cp] = v2fma(mx, v2ld(&W2c[(2*p)*8   + 2*cp]), acc3[cp]);
                        acc3[cp] = v2fma(my, v2ld(&W2c[(2*p+1)*8 + 2*cp]), acc3[cp]);
                    }
                }
                #pragma unroll
                for (int cp = 0; cp < 4; ++cp) accoutp[cp] += v2max0(acc3[cp]);
            }
        }
        // Each lane owns node l outright: write this wave's partial directly.
        // (R6 bug was an extra shfl_xor reduce here, mixing 8 different nodes.)
        #pragma unroll
        for (int cp = 0; cp < 4; ++cp) {
            s_part[w][l][2*cp]   = accoutp[cp].x;
            s_part[w][l][2*cp+1] = accoutp[cp].y;
        }
        __syncthreads();

        // ---- C: GRU; wave w owns channels c = w*16..+15, packed over k. ----
        v2f hp[32];                            // h state as 32 pairs (static idx only)
        #pragma unroll
        for (int q = 0; q < 16; ++q)
            *(float4*)&hp[2*q] = *(const float4*)&s_hx[l][q*4];
        float x8[8];
        #pragma unroll
        for (int k = 0; k < 8; ++k)
            x8[k] = s_part[0][l][k] + s_part[1][l][k] + s_part[2][l][k] + s_part[3][l][k];
        const v2f xp0 = {x8[0], x8[1]}, xp1 = {x8[2], x8[3]},
                  xp2 = {x8[4], x8[5]}, xp3 = {x8[6], x8[7]};
        __syncthreads();                       // all lanes captured h_old before writes

        #pragma unroll 1
        for (int cc = 0; cc < 16; ++cc) {
            const int c = w*16 + cc;           // uniform -> all weight reads s_load
            v2f ar = {0.f,0.f}, az = {0.f,0.f}, an = {0.f,0.f}, ah = {0.f,0.f};
            ar = v2fma(xp0, v2ld(&Wih[c*8+0]), ar);
            ar = v2fma(xp1, v2ld(&Wih[c*8+2]), ar);
            ar = v2fma(xp2, v2ld(&Wih[c*8+4]), ar);
            ar = v2fma(xp3, v2ld(&Wih[c*8+6]), ar);
            az = v2fma(xp0, v2ld(&Wih[(64+c)*8+0]), az);
            az = v2fma(xp1, v2ld(&Wih[(64+c)*8+2]), az);
            az = v2fma(xp2, v2ld(&Wih[(64+c)*8+4]), az);
            az = v2fma(xp3, v2ld(&Wih[(64+c)*8+6]), az);
            an = v2fma(xp0, v2ld(&Wih[(128+c)*8+0]), an);
            an = v2fma(xp1, v2ld(&Wih[(128+c)*8+2]), an);
            an = v2fma(xp2, v2ld(&Wih[(128+c)*8+4]), an);
            an = v2fma(xp3, v2ld(&Wih[(128+c)*8+6]), an);
            #pragma unroll
            for (int q = 0; q < 32; ++q) {
                ar = v2fma(hp[q], v2ld(&Whh[c*64       + 2*q]), ar);
                az = v2fma(hp[q], v2ld(&Whh[(64+c)*64  + 2*q]), az);
                ah = v2fma(hp[q], v2ld(&Whh[(128+c)*64 + 2*q]), ah);
            }
            const float r0 = bih[c]     + bhh[c]     + ar.x + ar.y;
            const float z0 = bih[64+c]  + bhh[64+c]  + az.x + az.y;
            const float n0 = bih[128+c]              + an.x + an.y;
            const float nh = bhh[128+c]              + ah.x + ah.y;
            const float rr = sigm_(r0);
            const float zz = sigm_(z0);
            const float nn = tanh_(n0 + rr*nh);
            const float hold = s_hx[l][c];     // still old: only this lane writes (l,c)
            s_hx[l][c] = (1.0f - zz)*nn + zz*hold;
        }
        __syncthreads();

        // ---- D: gru_read = hx_new @ W4 + b4; wave w does channels w*2, w*2+1 ----
        {
            const int c0 = w*2, c1 = w*2 + 1;
            float acc0 = b4[c0], acc1 = b4[c1];
            #pragma unroll
            for (int q = 0; q < 16; ++q) {
                const float4 hv = *(const float4*)&s_hx[l][q*4];
                acc0 = __builtin_fmaf(hv.x, W4[(q*4+0)*8 + c0], acc0);
                acc0 = __builtin_fmaf(hv.y, W4[(q*4+1)*8 + c0], acc0);
                acc0 = __builtin_fmaf(hv.z, W4[(q*4+2)*8 + c0], acc0);
                acc0 = __builtin_fmaf(hv.w, W4[(q*4+3)*8 + c0], acc0);
                acc1 = __builtin_fmaf(hv.x, W4[(q*4+0)*8 + c1], acc1);
                acc1 = __builtin_fmaf(hv.y, W4[(q*4+1)*8 + c1], acc1);
                acc1 = __builtin_fmaf(hv.z, W4[(q*4+2)*8 + c1], acc1);
                acc1 = __builtin_fmaf(hv.w, W4[(q*4+3)*8 + c1], acc1);
            }
            s_nodes[l][c0] = acc0;
            s_nodes[l][c1] = acc1;
        }
        __syncthreads();
    }

    // ---- final MLP: 8 -> 64 -> 32 -> 4 ----
    {
        float nd[8];
        *(float4*)&nd[0] = *(const float4*)&s_nodes[l][0];
        *(float4*)&nd[4] = *(const float4*)&s_nodes[l][4];
        #pragma unroll
        for (int hh = 0; hh < 16; ++hh) {
            const int hO = w*16 + hh;
            float acc = b3a[hO];
            #pragma unroll
            for (int k = 0; k < 8; ++k) acc = __builtin_fmaf(nd[k], W3a[k*64 + hO], acc);
            s_A1[l][hO] = acc;
        }
    }
    __syncthreads();
    {
        float acc[8];
        #pragma unroll
        for (int jj = 0; jj < 8; ++jj) acc[jj] = b3b[w*8 + jj];
        #pragma unroll
        for (int q = 0; q < 16; ++q) {
            const float4 v = *(const float4*)&s_A1[l][q*4];
            #pragma unroll
            for (int jj = 0; jj < 8; ++jj) {
                const int n = w*8 + jj;
                acc[jj] = __builtin_fmaf(v.x, W3b[(q*4+0)*32 + n], acc[jj]);
                acc[jj] = __builtin_fmaf(v.y, W3b[(q*4+1)*32 + n], acc[jj]);
                acc[jj] = __builtin_fmaf(v.z, W3b[(q*4+2)*32 + n], acc[jj]);
                acc[jj] = __builtin_fmaf(v.w, W3b[(q*4+3)*32 + n], acc[jj]);
            }
        }
        #pragma unroll
        for (int jj = 0; jj < 8; ++jj) s_B1[l][w*8 + jj] = acc[jj];
    }
    __syncthreads();
    {
        float acc = b3c[w];
        #pragma unroll
        for (int n = 0; n < 32; ++n)
            acc = __builtin_fmaf(s_B1[l][n], W3c[n*4 + w], acc);
        out[((size_t)bg*32 + a)*4 + w] = acc;
    }
}

extern "C" void kernel_launch(void* const* d_in, const int* in_sizes, int n_in,
                              void* d_out, int out_size, void* d_ws, size_t ws_size,
                              hipStream_t stream)
{
    const float* init_features = (const float*)d_in[0];
    const float* edge_weight   = (const float*)d_in[1];
    const float* noise_info    = (const float*)d_in[2];
    const float* hx_init       = (const float*)d_in[3];
    /* d_in[4] = cons — unused by the reference forward */
    const float* x_hat = (const float*)d_in[5];
    const float* var_i = (const float*)d_in[6];
    const float* W1a = (const float*)d_in[7];  const float* b1a = (const float*)d_in[8];
    const float* W2a = (const float*)d_in[9];  const float* b2a = (const float*)d_in[10];
    const float* W2b = (const float*)d_in[11]; const float* b2b = (const float*)d_in[12];
    const float* W2c = (const float*)d_in[13]; const float* b2c = (const float*)d_in[14];
    const float* W3a = (const float*)d_in[15]; const float* b3a = (const float*)d_in[16];
    const float* W3b = (const float*)d_in[17]; const float* b3b = (const float*)d_in[18];
    const float* W3c = (const float*)d_in[19]; const float* b3c = (const float*)d_in[20];
    const float* Wih = (const float*)d_in[21]; const float* Whh = (const float*)d_in[22];
    const float* bih = (const float*)d_in[23]; const float* bhh = (const float*)d_in[24];
    const float* W4  = (const float*)d_in[25]; const float* b4  = (const float*)d_in[26];

    gnn_fused<<<dim3(512), dim3(256), 0, stream>>>(
        init_features, edge_weight, noise_info, hx_init, x_hat, var_i,
        W1a, b1a, W2a, b2a, W2b, b2b, W2c, b2c,
        W3a, b3a, W3b, b3b, W3c, b3c,
        Wih, Whh, bih, bhh, W4, b4, (float*)d_out);
}